// Round 14
// baseline (246.808 us; speedup 1.0000x reference)
//
#include <hip/hip_runtime.h>
#include <hip/hip_bf16.h>

#define NN 4096
#define DD 256
#define OO 256
#define NR 8                   // adjacency rows per K2 block
#define ROWF (NN * 3)          // floats per adjacency row
#define NSPLIT 8
#define NB2 (NN / NR)          // 512 k2 blocks

typedef __attribute__((ext_vector_type(4))) float f32x4;
typedef __attribute__((ext_vector_type(8))) short bf16x8;
typedef __attribute__((ext_vector_type(8))) short short8;
typedef __attribute__((ext_vector_type(4))) unsigned int u32x4;
typedef __attribute__((ext_vector_type(2))) unsigned int u32x2;

__device__ __forceinline__ short f2bfs(float f) {
    __hip_bfloat16 h = __float2bfloat16(f);
    short s;
    __builtin_memcpy(&s, &h, 2);
    return s;
}

__device__ __forceinline__ float bfs2f(unsigned short u) {
    unsigned int v = (unsigned int)u << 16;
    float f;
    __builtin_memcpy(&f, &v, 4);
    return f;
}

__device__ __forceinline__ unsigned pack2(float a, float b) {
    return (unsigned)(unsigned short)f2bfs(a)
         | ((unsigned)(unsigned short)f2bfs(b) << 16);
}

// K1: XWTb[m/8][o/16][16][8] bf16 = (X@Wf)[m][o] (k4 B-frag tiled). 512 blocks.
__global__ __launch_bounds__(256) void k1_xwt(
    const float* __restrict__ X, const float* __restrict__ W,
    unsigned short* __restrict__ XWTb)
{
    __shared__ float xs[8][DD];
    const int t = threadIdx.x;
    const int m0 = blockIdx.x * 8;

    #pragma unroll
    for (int i = 0; i < 8; ++i)
        xs[i][t] = X[(size_t)(m0 + i) * DD + t];
    __syncthreads();

    float acc[8];
    #pragma unroll
    for (int m = 0; m < 8; ++m) acc[m] = 0.f;

    for (int k0 = 0; k0 < DD; k0 += 4) {
        float w0 = W[(size_t)(k0 + 0) * OO + t];
        float w1 = W[(size_t)(k0 + 1) * OO + t];
        float w2 = W[(size_t)(k0 + 2) * OO + t];
        float w3 = W[(size_t)(k0 + 3) * OO + t];
        #pragma unroll
        for (int m = 0; m < 8; ++m) {
            const f32x4 xv = *reinterpret_cast<const f32x4*>(&xs[m][k0]);
            acc[m] = fmaf(xv[0], w0, acc[m]);
            acc[m] = fmaf(xv[1], w1, acc[m]);
            acc[m] = fmaf(xv[2], w2, acc[m]);
            acc[m] = fmaf(xv[3], w3, acc[m]);
        }
    }

    unsigned int p[4];
    #pragma unroll
    for (int i = 0; i < 4; ++i)
        p[i] = pack2(acc[2 * i], acc[2 * i + 1]);
    unsigned short* dst = XWTb
        + ((((size_t)(m0 >> 3) * (OO / 16) + (t >> 4)) * 16) + (t & 15)) * 8;
    *reinterpret_cast<u32x4*>(dst) = (u32x4){p[0], p[1], p[2], p[3]};
}

// K2: probe-disciplined streamer (r13 structure), adjacency partials now via
// fp32 atomicAdd into the 48KB agg buffer (L2-resident; 512 updates/address
// spread over the kernel lifetime -> serialization fully hidden).
__global__ __launch_bounds__(1024, 8) void k2_stream(
    const float* __restrict__ Adj, const float* __restrict__ Beta,
    float* __restrict__ agg, unsigned short* __restrict__ BetaTb)
{
    __shared__ unsigned short bsm16[NR * NN];   // 64 KB
    const int t = threadIdx.x;
    const int nb = blockIdx.x;       // 0..511
    const int n0 = nb * NR;

    int fpos[3], y0[3], rr[3];
    #pragma unroll
    for (int p = 0; p < 3; ++p) {
        fpos[p] = p * NN + 4 * t;
        y0[p] = fpos[p] / 3;
        rr[p] = fpos[p] - 3 * y0[p];
    }

    // 1. register staging of Beta
    f32x4 br[NR];
    #pragma unroll
    for (int n = 0; n < NR; ++n)
        br[n] = *reinterpret_cast<const f32x4*>(Beta + (size_t)(n0 + n) * NN + 4 * t);

    // 2. BetaTb emit from regs (u32x4, fully coalesced, private slab)
    #pragma unroll
    for (int c = 0; c < 2; ++c) {
        unsigned wlo[4], whi[4];
        #pragma unroll
        for (int q = 0; q < 4; ++q) {
            wlo[q] = pack2(br[4 * c + 0][q], br[4 * c + 1][q]);
            whi[q] = pack2(br[4 * c + 2][q], br[4 * c + 3][q]);
        }
        u32x4* d = reinterpret_cast<u32x4*>(
            BetaTb + ((size_t)(2 * nb + c) * NN + 4 * t) * 4);
        d[0] = (u32x4){wlo[0], whi[0], wlo[1], whi[1]};
        d[1] = (u32x4){wlo[2], whi[2], wlo[3], whi[3]};
    }

    // 3. pack to LDS [n][y]
    #pragma unroll
    for (int n = 0; n < NR; ++n) {
        const unsigned lo = pack2(br[n][0], br[n][1]);
        const unsigned hi = pack2(br[n][2], br[n][3]);
        *reinterpret_cast<u32x2*>(&bsm16[n * NN + 4 * t]) = (u32x2){lo, hi};
    }
    __syncthreads();

    // 4. stream
    f32x4 acc[3];
    #pragma unroll
    for (int p = 0; p < 3; ++p) acc[p] = (f32x4){0.f, 0.f, 0.f, 0.f};

    const float* arow = Adj + (size_t)n0 * ROWF;
    #pragma unroll 1
    for (int n = 0; n < NR; ++n) {
        f32x4 av[3];
        #pragma unroll
        for (int p = 0; p < 3; ++p)
            av[p] = __builtin_nontemporal_load(
                reinterpret_cast<const f32x4*>(arow + fpos[p]));
        #pragma unroll
        for (int p = 0; p < 3; ++p) {
            const float bl = bfs2f(bsm16[n * NN + y0[p]]);
            const float bh = bfs2f(bsm16[n * NN + y0[p] + 1]);
            #pragma unroll
            for (int q = 0; q < 4; ++q) {
                const float w = (rr[p] + q < 3) ? bl : bh;
                acc[p][q] = fmaf(w, av[p][q], acc[p][q]);
            }
        }
        arow += ROWF;
    }

    // 5. adjacency partial -> fp32 atomics (4 consecutive addrs per thread)
    #pragma unroll
    for (int p = 0; p < 3; ++p)
        #pragma unroll
        for (int q = 0; q < 4; ++q)
            atomicAdd(&agg[fpos[p] + q], acc[p][q]);
}

// K4: gpart[sp][y][o] bf16 = sum_{n in split} Beta[n,y]*XW[n,o].
// grid (64 y-blocks, NSPLIT), 256 thr = 4 waves; av prefetched one K-step ahead.
__global__ __launch_bounds__(256) void k4_gemm(
    const unsigned short* __restrict__ BetaTb, const unsigned short* __restrict__ XWTb,
    unsigned short* __restrict__ gpart, int clen)
{
    const int t = threadIdx.x;
    const int lane = t & 63;
    const int w = t >> 6;
    const int g16 = lane >> 4, r16 = lane & 15;
    const int y0 = blockIdx.x * 64 + 16 * w;
    const int sp = blockIdx.y;
    const int nb = sp * clen;
    const int ksteps = clen / 32;

    f32x4 acc[16];
    #pragma unroll
    for (int f = 0; f < 16; ++f) acc[f] = (f32x4){0.f, 0.f, 0.f, 0.f};

    const int yy = y0 + r16;
    #define AV_LD(kc, half)                                                     \
        *reinterpret_cast<const u32x2*>(                                        \
            BetaTb + (((size_t)((nb >> 2) + (kc) * 8 + 2 * g16 + (half)) * NN + yy)) * 4)

    u32x2 a0 = AV_LD(0, 0), a1 = AV_LD(0, 1);

    for (int kc = 0; kc < ksteps; ++kc) {
        bf16x8 av;
        {
            u32x4 tmp = (u32x4){a0[0], a0[1], a1[0], a1[1]};
            __builtin_memcpy(&av, &tmp, 16);
        }
        if (kc + 1 < ksteps) {
            a0 = AV_LD(kc + 1, 0);
            a1 = AV_LD(kc + 1, 1);
        }
        const int mc = ((nb >> 3) + kc * 4) + g16;
        const unsigned short* xb = XWTb + (((size_t)mc * 16) * 16 + r16) * 8;
        #pragma unroll
        for (int f = 0; f < 16; ++f) {
            const bf16x8 bv = *reinterpret_cast<const bf16x8*>(xb + (size_t)f * 128);
            acc[f] = __builtin_amdgcn_mfma_f32_16x16x32_bf16(av, bv, acc[f], 0, 0, 0);
        }
    }
    #undef AV_LD

    unsigned short* gp = gpart + (size_t)sp * NN * OO;
    #pragma unroll
    for (int f = 0; f < 16; ++f) {
        const int o = 16 * f + r16;
        #pragma unroll
        for (int r = 0; r < 4; ++r)
            gp[(size_t)(y0 + 4 * g16 + r) * OO + o] = (unsigned short)f2bfs(acc[f][r]);
    }
}

// K3: out[y,o] = sum_sp gpart(bf16) + agg[y]@Wa + bias. agg is L2-resident.
__global__ __launch_bounds__(256) void k3_final(
    const unsigned short* __restrict__ gpart, const float* __restrict__ agg,
    const float* __restrict__ W, const float* __restrict__ bias,
    float* __restrict__ Out)
{
    __shared__ float af[8][3];
    const int t = threadIdx.x;
    const int yb = blockIdx.x * 8;

    if (t < 24)
        af[t / 3][t % 3] = agg[yb * 3 + t];
    __syncthreads();

    const int idx = blockIdx.x * 256 + t;
    const int y = idx >> 5;              // 8 y's per block
    const int o0 = (idx & 31) * 8;
    const int yl = y & 7;

    float s[8];
    #pragma unroll
    for (int j = 0; j < 8; ++j) s[j] = 0.f;
    #pragma unroll
    for (int sp = 0; sp < NSPLIT; ++sp) {
        const short8 v = *reinterpret_cast<const short8*>(
            gpart + (size_t)sp * NN * OO + (size_t)y * OO + o0);
        #pragma unroll
        for (int j = 0; j < 8; ++j)
            s[j] += bfs2f((unsigned short)v[j]);
    }

    const float a0 = af[yl][0], a1 = af[yl][1], a2 = af[yl][2];
    float r[8];
    #pragma unroll
    for (int j = 0; j < 8; ++j) {
        const int oo = o0 + j;
        r[j] = s[j] + a0 * W[(size_t)(DD + 0) * OO + oo]
                    + a1 * W[(size_t)(DD + 1) * OO + oo]
                    + a2 * W[(size_t)(DD + 2) * OO + oo]
                    + bias[oo];
    }
    float* od = Out + (size_t)y * OO + o0;
    *reinterpret_cast<f32x4*>(od)     = (f32x4){r[0], r[1], r[2], r[3]};
    *reinterpret_cast<f32x4*>(od + 4) = (f32x4){r[4], r[5], r[6], r[7]};
}

extern "C" void kernel_launch(void* const* d_in, const int* in_sizes, int n_in,
                              void* d_out, int out_size, void* d_ws, size_t ws_size,
                              hipStream_t stream) {
    (void)in_sizes; (void)n_in; (void)out_size; (void)ws_size;
    const float* adj  = (const float*)d_in[0];  // (N, N, C)
    const float* X    = (const float*)d_in[1];  // (N, D)
    const float* Beta = (const float*)d_in[2];  // (N, N)
    const float* W    = (const float*)d_in[3];  // (D+C, O)
    const float* bias = (const float*)d_in[4];  // (O)
    float* out = (float*)d_out;                 // (N, O) fp32

    const size_t xwt_b   = (size_t)OO * NN * 2;              // 2 MB
    const size_t betat_b = (size_t)NN * NN * 2;              // 32 MB
    const size_t gpart_b = (size_t)NSPLIT * NN * OO * 2;     // 16 MB

    char* p = (char*)d_ws;
    unsigned short* XWTb   = (unsigned short*)p;            p += xwt_b;
    unsigned short* BetaTb = (unsigned short*)p;            p += betat_b;
    unsigned short* gpart  = (unsigned short*)p;            p += gpart_b;
    float*          agg    = (float*)p;                     // 48 KB

    const int clen = NN / NSPLIT;

    hipMemsetAsync(agg, 0, (size_t)ROWF * 4, stream);
    k1_xwt<<<dim3(NN / 8), dim3(256), 0, stream>>>(X, W, XWTb);
    k2_stream<<<dim3(NB2), dim3(1024), 0, stream>>>(adj, Beta, agg, BetaTb);
    k4_gemm<<<dim3(NN / 64, NSPLIT), dim3(256), 0, stream>>>(BetaTb, XWTb, gpart, clen);
    k3_final<<<dim3(NN / 8), dim3(256), 0, stream>>>(gpart, agg, W, bias, out);
}

// Round 15
// 134.899 us; speedup vs baseline: 1.8296x; 1.8296x over previous
//
#include <hip/hip_runtime.h>
#include <hip/hip_bf16.h>

#define NN 4096
#define DD 256
#define OO 256
#define NR 8                   // adjacency rows per K2 block
#define ROWF (NN * 3)          // floats per adjacency row
#define NSPLIT 8
#define NB2 (NN / NR)          // 512 k2 blocks

typedef __attribute__((ext_vector_type(4))) float f32x4;
typedef __attribute__((ext_vector_type(8))) short bf16x8;
typedef __attribute__((ext_vector_type(8))) short short8;
typedef __attribute__((ext_vector_type(4))) unsigned int u32x4;
typedef __attribute__((ext_vector_type(2))) unsigned int u32x2;

__device__ __forceinline__ short f2bfs(float f) {
    __hip_bfloat16 h = __float2bfloat16(f);
    short s;
    __builtin_memcpy(&s, &h, 2);
    return s;
}

__device__ __forceinline__ float bfs2f(unsigned short u) {
    unsigned int v = (unsigned int)u << 16;
    float f;
    __builtin_memcpy(&f, &v, 4);
    return f;
}

__device__ __forceinline__ unsigned pack2(float a, float b) {
    return (unsigned)(unsigned short)f2bfs(a)
         | ((unsigned)(unsigned short)f2bfs(b) << 16);
}

// K1: XWTb[m/8][o/16][16][8] bf16 = (X@Wf)[m][o] (k4 B-frag tiled). 512 blocks.
__global__ __launch_bounds__(256) void k1_xwt(
    const float* __restrict__ X, const float* __restrict__ W,
    unsigned short* __restrict__ XWTb)
{
    __shared__ float xs[8][DD];
    const int t = threadIdx.x;
    const int m0 = blockIdx.x * 8;

    #pragma unroll
    for (int i = 0; i < 8; ++i)
        xs[i][t] = X[(size_t)(m0 + i) * DD + t];
    __syncthreads();

    float acc[8];
    #pragma unroll
    for (int m = 0; m < 8; ++m) acc[m] = 0.f;

    for (int k0 = 0; k0 < DD; k0 += 4) {
        float w0 = W[(size_t)(k0 + 0) * OO + t];
        float w1 = W[(size_t)(k0 + 1) * OO + t];
        float w2 = W[(size_t)(k0 + 2) * OO + t];
        float w3 = W[(size_t)(k0 + 3) * OO + t];
        #pragma unroll
        for (int m = 0; m < 8; ++m) {
            const f32x4 xv = *reinterpret_cast<const f32x4*>(&xs[m][k0]);
            acc[m] = fmaf(xv[0], w0, acc[m]);
            acc[m] = fmaf(xv[1], w1, acc[m]);
            acc[m] = fmaf(xv[2], w2, acc[m]);
            acc[m] = fmaf(xv[3], w3, acc[m]);
        }
    }

    unsigned int p[4];
    #pragma unroll
    for (int i = 0; i < 4; ++i)
        p[i] = pack2(acc[2 * i], acc[2 * i + 1]);
    unsigned short* dst = XWTb
        + ((((size_t)(m0 >> 3) * (OO / 16) + (t >> 4)) * 16) + (t & 15)) * 8;
    *reinterpret_cast<u32x4*>(dst) = (u32x4){p[0], p[1], p[2], p[3]};
}

// K2: probe-disciplined streamer (r13-proven), NR=8, ONE barrier.
//  1. load 8 Beta rows x 4 cols into regs (dense dwordx4)
//  2. emit BetaTb[n/4][y][4] straight from regs (u32x4, fully coalesced)
//  3. pack bf16 -> LDS bsm16[n][y] (8B writes, 2-way conflict = free)
//  4. one __syncthreads
//  5. rolled stream: 3 nontemporal dwordx4/row + bf16 weights from LDS, no barriers
//  6. bf16 apart emit
__global__ __launch_bounds__(1024, 8) void k2_stream(
    const float* __restrict__ Adj, const float* __restrict__ Beta,
    unsigned short* __restrict__ apart, unsigned short* __restrict__ BetaTb)
{
    __shared__ unsigned short bsm16[NR * NN];   // 64 KB
    const int t = threadIdx.x;
    const int nb = blockIdx.x;       // 0..511
    const int n0 = nb * NR;

    int fpos[3], y0[3], rr[3];
    #pragma unroll
    for (int p = 0; p < 3; ++p) {
        fpos[p] = p * NN + 4 * t;
        y0[p] = fpos[p] / 3;
        rr[p] = fpos[p] - 3 * y0[p];
    }

    // 1. register staging of Beta
    f32x4 br[NR];
    #pragma unroll
    for (int n = 0; n < NR; ++n)
        br[n] = *reinterpret_cast<const f32x4*>(Beta + (size_t)(n0 + n) * NN + 4 * t);

    // 2. BetaTb emit from regs (u32x4, fully coalesced, private slab)
    #pragma unroll
    for (int c = 0; c < 2; ++c) {
        unsigned wlo[4], whi[4];
        #pragma unroll
        for (int q = 0; q < 4; ++q) {
            wlo[q] = pack2(br[4 * c + 0][q], br[4 * c + 1][q]);
            whi[q] = pack2(br[4 * c + 2][q], br[4 * c + 3][q]);
        }
        u32x4* d = reinterpret_cast<u32x4*>(
            BetaTb + ((size_t)(2 * nb + c) * NN + 4 * t) * 4);
        d[0] = (u32x4){wlo[0], whi[0], wlo[1], whi[1]};
        d[1] = (u32x4){wlo[2], whi[2], wlo[3], whi[3]};
    }

    // 3. pack to LDS [n][y]
    #pragma unroll
    for (int n = 0; n < NR; ++n) {
        const unsigned lo = pack2(br[n][0], br[n][1]);
        const unsigned hi = pack2(br[n][2], br[n][3]);
        *reinterpret_cast<u32x2*>(&bsm16[n * NN + 4 * t]) = (u32x2){lo, hi};
    }
    __syncthreads();

    // 5. stream
    f32x4 acc[3];
    #pragma unroll
    for (int p = 0; p < 3; ++p) acc[p] = (f32x4){0.f, 0.f, 0.f, 0.f};

    const float* arow = Adj + (size_t)n0 * ROWF;
    #pragma unroll 1
    for (int n = 0; n < NR; ++n) {
        f32x4 av[3];
        #pragma unroll
        for (int p = 0; p < 3; ++p)
            av[p] = __builtin_nontemporal_load(
                reinterpret_cast<const f32x4*>(arow + fpos[p]));
        #pragma unroll
        for (int p = 0; p < 3; ++p) {
            const float bl = bfs2f(bsm16[n * NN + y0[p]]);
            const float bh = bfs2f(bsm16[n * NN + y0[p] + 1]);
            #pragma unroll
            for (int q = 0; q < 4; ++q) {
                const float w = (rr[p] + q < 3) ? bl : bh;
                acc[p][q] = fmaf(w, av[p][q], acc[p][q]);
            }
        }
        arow += ROWF;
    }

    // 6. adjacency partial: bf16, 3 x 8B coalesced stores
    unsigned short* op = apart + (size_t)nb * ROWF;
    #pragma unroll
    for (int p = 0; p < 3; ++p) {
        const unsigned lo = pack2(acc[p][0], acc[p][1]);
        const unsigned hi = pack2(acc[p][2], acc[p][3]);
        *reinterpret_cast<u32x2*>(op + fpos[p]) = (u32x2){lo, hi};
    }
}

// K4: gpart[sp][y][o] bf16 = sum_{n in split} Beta[n,y]*XW[n,o].
// grid (64 y-blocks, NSPLIT), 256 thr = 4 waves; av prefetched one K-step ahead.
__global__ __launch_bounds__(256) void k4_gemm(
    const unsigned short* __restrict__ BetaTb, const unsigned short* __restrict__ XWTb,
    unsigned short* __restrict__ gpart, int clen)
{
    const int t = threadIdx.x;
    const int lane = t & 63;
    const int w = t >> 6;
    const int g16 = lane >> 4, r16 = lane & 15;
    const int y0 = blockIdx.x * 64 + 16 * w;
    const int sp = blockIdx.y;
    const int nb = sp * clen;
    const int ksteps = clen / 32;

    f32x4 acc[16];
    #pragma unroll
    for (int f = 0; f < 16; ++f) acc[f] = (f32x4){0.f, 0.f, 0.f, 0.f};

    const int yy = y0 + r16;
    #define AV_LD(kc, half)                                                     \
        *reinterpret_cast<const u32x2*>(                                        \
            BetaTb + (((size_t)((nb >> 2) + (kc) * 8 + 2 * g16 + (half)) * NN + yy)) * 4)

    u32x2 a0 = AV_LD(0, 0), a1 = AV_LD(0, 1);

    for (int kc = 0; kc < ksteps; ++kc) {
        bf16x8 av;
        {
            u32x4 tmp = (u32x4){a0[0], a0[1], a1[0], a1[1]};
            __builtin_memcpy(&av, &tmp, 16);
        }
        if (kc + 1 < ksteps) {
            a0 = AV_LD(kc + 1, 0);
            a1 = AV_LD(kc + 1, 1);
        }
        const int mc = ((nb >> 3) + kc * 4) + g16;
        const unsigned short* xb = XWTb + (((size_t)mc * 16) * 16 + r16) * 8;
        #pragma unroll
        for (int f = 0; f < 16; ++f) {
            const bf16x8 bv = *reinterpret_cast<const bf16x8*>(xb + (size_t)f * 128);
            acc[f] = __builtin_amdgcn_mfma_f32_16x16x32_bf16(av, bv, acc[f], 0, 0, 0);
        }
    }
    #undef AV_LD

    unsigned short* gp = gpart + (size_t)sp * NN * OO;
    #pragma unroll
    for (int f = 0; f < 16; ++f) {
        const int o = 16 * f + r16;
        #pragma unroll
        for (int r = 0; r < 4; ++r)
            gp[(size_t)(y0 + 4 * g16 + r) * OO + o] = (unsigned short)f2bfs(acc[f][r]);
    }
}

// K3 (k2b fused in): phase 1 reduces this block's 24 apart cells over all 512
// slabs (48 contiguous bytes per slab, latency-hidden); phase 2 = final combine.
__global__ __launch_bounds__(256) void k3_final(
    const unsigned short* __restrict__ gpart, const unsigned short* __restrict__ apart,
    const float* __restrict__ W, const float* __restrict__ bias,
    float* __restrict__ Out)
{
    __shared__ float red[24][11];   // 24 cells x 10 groups (+pad)
    __shared__ float af[8][3];
    const int t = threadIdx.x;
    const int yb = blockIdx.x * 8;

    // phase 1a: 240 threads, cell j = t%24, slab-group g = t/24
    if (t < 240) {
        const int j = t % 24, g = t / 24;
        const int b0 = g * 52;
        const int b1 = (b0 + 52 < NB2) ? b0 + 52 : NB2;
        float s = 0.f;
        for (int nb = b0; nb < b1; ++nb)
            s += bfs2f(apart[(size_t)nb * ROWF + yb * 3 + j]);
        red[j][g] = s;
    }
    __syncthreads();
    // phase 1b: fold the 10 groups
    if (t < 24) {
        float s = 0.f;
        #pragma unroll
        for (int g = 0; g < 10; ++g) s += red[t][g];
        af[t / 3][t % 3] = s;
    }
    __syncthreads();

    const int idx = blockIdx.x * 256 + t;
    const int y = idx >> 5;              // 8 y's per block
    const int o0 = (idx & 31) * 8;
    const int yl = y & 7;

    float s[8];
    #pragma unroll
    for (int j = 0; j < 8; ++j) s[j] = 0.f;
    #pragma unroll
    for (int sp = 0; sp < NSPLIT; ++sp) {
        const short8 v = *reinterpret_cast<const short8*>(
            gpart + (size_t)sp * NN * OO + (size_t)y * OO + o0);
        #pragma unroll
        for (int j = 0; j < 8; ++j)
            s[j] += bfs2f((unsigned short)v[j]);
    }

    const float a0 = af[yl][0], a1 = af[yl][1], a2 = af[yl][2];
    float r[8];
    #pragma unroll
    for (int j = 0; j < 8; ++j) {
        const int oo = o0 + j;
        r[j] = s[j] + a0 * W[(size_t)(DD + 0) * OO + oo]
                    + a1 * W[(size_t)(DD + 1) * OO + oo]
                    + a2 * W[(size_t)(DD + 2) * OO + oo]
                    + bias[oo];
    }
    float* od = Out + (size_t)y * OO + o0;
    *reinterpret_cast<f32x4*>(od)     = (f32x4){r[0], r[1], r[2], r[3]};
    *reinterpret_cast<f32x4*>(od + 4) = (f32x4){r[4], r[5], r[6], r[7]};
}

extern "C" void kernel_launch(void* const* d_in, const int* in_sizes, int n_in,
                              void* d_out, int out_size, void* d_ws, size_t ws_size,
                              hipStream_t stream) {
    (void)in_sizes; (void)n_in; (void)out_size; (void)ws_size;
    const float* adj  = (const float*)d_in[0];  // (N, N, C)
    const float* X    = (const float*)d_in[1];  // (N, D)
    const float* Beta = (const float*)d_in[2];  // (N, N)
    const float* W    = (const float*)d_in[3];  // (D+C, O)
    const float* bias = (const float*)d_in[4];  // (O)
    float* out = (float*)d_out;                 // (N, O) fp32

    const size_t xwt_b   = (size_t)OO * NN * 2;              // 2 MB
    const size_t betat_b = (size_t)NN * NN * 2;              // 32 MB
    const size_t gpart_b = (size_t)NSPLIT * NN * OO * 2;     // 16 MB

    char* p = (char*)d_ws;
    unsigned short* XWTb   = (unsigned short*)p;            p += xwt_b;
    unsigned short* BetaTb = (unsigned short*)p;            p += betat_b;
    unsigned short* gpart  = (unsigned short*)p;            p += gpart_b;
    unsigned short* apart  = (unsigned short*)p;            // 12 MB

    const int clen = NN / NSPLIT;

    k1_xwt<<<dim3(NN / 8), dim3(256), 0, stream>>>(X, W, XWTb);
    k2_stream<<<dim3(NB2), dim3(1024), 0, stream>>>(adj, Beta, apart, BetaTb);
    k4_gemm<<<dim3(NN / 64, NSPLIT), dim3(256), 0, stream>>>(BetaTb, XWTb, gpart, clen);
    k3_final<<<dim3(NN / 8), dim3(256), 0, stream>>>(gpart, apart, W, bias, out);
}

// Round 16
// 119.257 us; speedup vs baseline: 2.0695x; 1.1312x over previous
//
#include <hip/hip_runtime.h>
#include <hip/hip_bf16.h>

#define NN 4096
#define DD 256
#define OO 256
#define NR 8                   // adjacency rows per K2 block
#define ROWF (NN * 3)          // floats per adjacency row
#define NSPLIT 8
#define NAGG 32                // k2b row-groups
#define NB2 (NN / NR)          // 512 k2 blocks

typedef __attribute__((ext_vector_type(4))) float f32x4;
typedef __attribute__((ext_vector_type(8))) short bf16x8;
typedef __attribute__((ext_vector_type(8))) short short8;
typedef __attribute__((ext_vector_type(4))) unsigned int u32x4;
typedef __attribute__((ext_vector_type(2))) unsigned int u32x2;

__device__ __forceinline__ short f2bfs(float f) {
    __hip_bfloat16 h = __float2bfloat16(f);
    short s;
    __builtin_memcpy(&s, &h, 2);
    return s;
}

__device__ __forceinline__ float bfs2f(unsigned short u) {
    unsigned int v = (unsigned int)u << 16;
    float f;
    __builtin_memcpy(&f, &v, 4);
    return f;
}

__device__ __forceinline__ unsigned pack2(float a, float b) {
    return (unsigned)(unsigned short)f2bfs(a)
         | ((unsigned)(unsigned short)f2bfs(b) << 16);
}

// K1: XWTb[m/8][o/16][16][8] bf16 = (X@Wf)[m][o] (k4 B-frag tiled). 512 blocks.
__global__ __launch_bounds__(256) void k1_xwt(
    const float* __restrict__ X, const float* __restrict__ W,
    unsigned short* __restrict__ XWTb)
{
    __shared__ float xs[8][DD];
    const int t = threadIdx.x;
    const int m0 = blockIdx.x * 8;

    #pragma unroll
    for (int i = 0; i < 8; ++i)
        xs[i][t] = X[(size_t)(m0 + i) * DD + t];
    __syncthreads();

    float acc[8];
    #pragma unroll
    for (int m = 0; m < 8; ++m) acc[m] = 0.f;

    for (int k0 = 0; k0 < DD; k0 += 4) {
        float w0 = W[(size_t)(k0 + 0) * OO + t];
        float w1 = W[(size_t)(k0 + 1) * OO + t];
        float w2 = W[(size_t)(k0 + 2) * OO + t];
        float w3 = W[(size_t)(k0 + 3) * OO + t];
        #pragma unroll
        for (int m = 0; m < 8; ++m) {
            const f32x4 xv = *reinterpret_cast<const f32x4*>(&xs[m][k0]);
            acc[m] = fmaf(xv[0], w0, acc[m]);
            acc[m] = fmaf(xv[1], w1, acc[m]);
            acc[m] = fmaf(xv[2], w2, acc[m]);
            acc[m] = fmaf(xv[3], w3, acc[m]);
        }
    }

    unsigned int p[4];
    #pragma unroll
    for (int i = 0; i < 4; ++i)
        p[i] = pack2(acc[2 * i], acc[2 * i + 1]);
    unsigned short* dst = XWTb
        + ((((size_t)(m0 >> 3) * (OO / 16) + (t >> 4)) * 16) + (t & 15)) * 8;
    *reinterpret_cast<u32x4*>(dst) = (u32x4){p[0], p[1], p[2], p[3]};
}

// K2: probe-disciplined streamer (r13-proven), NR=8, ONE barrier.
// BetaTb emission removed: k4 now reads Beta directly (L3-resident thanks to
// nontemporal adjacency loads here). k2 writes only the 12 MB bf16 apart.
__global__ __launch_bounds__(1024, 8) void k2_stream(
    const float* __restrict__ Adj, const float* __restrict__ Beta,
    unsigned short* __restrict__ apart)
{
    __shared__ unsigned short bsm16[NR * NN];   // 64 KB
    const int t = threadIdx.x;
    const int nb = blockIdx.x;       // 0..511
    const int n0 = nb * NR;

    int fpos[3], y0[3], rr[3];
    #pragma unroll
    for (int p = 0; p < 3; ++p) {
        fpos[p] = p * NN + 4 * t;
        y0[p] = fpos[p] / 3;
        rr[p] = fpos[p] - 3 * y0[p];
    }

    // 1. register staging of Beta
    f32x4 br[NR];
    #pragma unroll
    for (int n = 0; n < NR; ++n)
        br[n] = *reinterpret_cast<const f32x4*>(Beta + (size_t)(n0 + n) * NN + 4 * t);

    // 2. pack to LDS [n][y]
    #pragma unroll
    for (int n = 0; n < NR; ++n) {
        const unsigned lo = pack2(br[n][0], br[n][1]);
        const unsigned hi = pack2(br[n][2], br[n][3]);
        *reinterpret_cast<u32x2*>(&bsm16[n * NN + 4 * t]) = (u32x2){lo, hi};
    }
    __syncthreads();

    // 3. stream
    f32x4 acc[3];
    #pragma unroll
    for (int p = 0; p < 3; ++p) acc[p] = (f32x4){0.f, 0.f, 0.f, 0.f};

    const float* arow = Adj + (size_t)n0 * ROWF;
    #pragma unroll 1
    for (int n = 0; n < NR; ++n) {
        f32x4 av[3];
        #pragma unroll
        for (int p = 0; p < 3; ++p)
            av[p] = __builtin_nontemporal_load(
                reinterpret_cast<const f32x4*>(arow + fpos[p]));
        #pragma unroll
        for (int p = 0; p < 3; ++p) {
            const float bl = bfs2f(bsm16[n * NN + y0[p]]);
            const float bh = bfs2f(bsm16[n * NN + y0[p] + 1]);
            #pragma unroll
            for (int q = 0; q < 4; ++q) {
                const float w = (rr[p] + q < 3) ? bl : bh;
                acc[p][q] = fmaf(w, av[p][q], acc[p][q]);
            }
        }
        arow += ROWF;
    }

    // 4. adjacency partial: bf16, 3 x 8B coalesced stores
    unsigned short* op = apart + (size_t)nb * ROWF;
    #pragma unroll
    for (int p = 0; p < 3; ++p) {
        const unsigned lo = pack2(acc[p][0], acc[p][1]);
        const unsigned hi = pack2(acc[p][2], acc[p][3]);
        *reinterpret_cast<u32x2*>(op + fpos[p]) = (u32x2){lo, hi};
    }
}

// K2b: agg2[g][i] = sum of 16 n-blocks of bf16 apart. grid (6, NAGG), short8 loads.
__global__ __launch_bounds__(256) void k2b_reduce(
    const unsigned short* __restrict__ apart, float* __restrict__ agg2)
{
    const int t = threadIdx.x;
    const int i0 = blockIdx.x * 2048 + t * 8;
    const int g = blockIdx.y;

    float s[8];
    #pragma unroll
    for (int j = 0; j < 8; ++j) s[j] = 0.f;

    #pragma unroll 4
    for (int r = 0; r < NB2 / NAGG; ++r) {
        const short8 v = *reinterpret_cast<const short8*>(
            apart + (size_t)(g * (NB2 / NAGG) + r) * ROWF + i0);
        #pragma unroll
        for (int j = 0; j < 8; ++j)
            s[j] += bfs2f((unsigned short)v[j]);
    }

    float* d = agg2 + (size_t)g * ROWF + i0;
    *reinterpret_cast<f32x4*>(d)     = (f32x4){s[0], s[1], s[2], s[3]};
    *reinterpret_cast<f32x4*>(d + 4) = (f32x4){s[4], s[5], s[6], s[7]};
}

// K4: gpart[sp][y][o] bf16 = sum_{n in split} Beta[n,y]*XW[n,o].
// A-frag assembled directly from fp32 Beta (L3-hot): 8 loads, each 64B per
// 16-lane group, prefetched one K-step ahead; same k-ordering as r13's BetaTb.
__global__ __launch_bounds__(256) void k4_gemm(
    const float* __restrict__ Beta, const unsigned short* __restrict__ XWTb,
    unsigned short* __restrict__ gpart, int clen)
{
    const int t = threadIdx.x;
    const int lane = t & 63;
    const int w = t >> 6;
    const int g16 = lane >> 4, r16 = lane & 15;
    const int y0 = blockIdx.x * 64 + 16 * w;
    const int sp = blockIdx.y;
    const int nb = sp * clen;
    const int ksteps = clen / 32;

    f32x4 acc[16];
    #pragma unroll
    for (int f = 0; f < 16; ++f) acc[f] = (f32x4){0.f, 0.f, 0.f, 0.f};

    // av[j] = Beta[nb + kc*32 + 8*g16 + j][y0 + r16]
    const float* bp = Beta + (size_t)(nb + 8 * g16) * NN + (y0 + r16);

    float bcur[8];
    #pragma unroll
    for (int j = 0; j < 8; ++j)
        bcur[j] = bp[(size_t)j * NN];

    for (int kc = 0; kc < ksteps; ++kc) {
        bf16x8 av;
        #pragma unroll
        for (int j = 0; j < 8; ++j)
            av[j] = f2bfs(bcur[j]);

        if (kc + 1 < ksteps) {
            const float* bn = bp + (size_t)(kc + 1) * 32 * NN;
            #pragma unroll
            for (int j = 0; j < 8; ++j)
                bcur[j] = bn[(size_t)j * NN];
        }

        const int mc = ((nb >> 3) + kc * 4) + g16;
        const unsigned short* xb = XWTb + (((size_t)mc * 16) * 16 + r16) * 8;
        #pragma unroll
        for (int f = 0; f < 16; ++f) {
            const bf16x8 bv = *reinterpret_cast<const bf16x8*>(xb + (size_t)f * 128);
            acc[f] = __builtin_amdgcn_mfma_f32_16x16x32_bf16(av, bv, acc[f], 0, 0, 0);
        }
    }

    unsigned short* gp = gpart + (size_t)sp * NN * OO;
    #pragma unroll
    for (int f = 0; f < 16; ++f) {
        const int o = 16 * f + r16;
        #pragma unroll
        for (int r = 0; r < 4; ++r)
            gp[(size_t)(y0 + 4 * g16 + r) * OO + o] = (unsigned short)f2bfs(acc[f][r]);
    }
}

// K3: out[y,o] = sum_sp gpart(bf16) + (sum_g agg2[g][y]) @ Wa + bias.
__global__ __launch_bounds__(256) void k3_final(
    const unsigned short* __restrict__ gpart, const float* __restrict__ agg2,
    const float* __restrict__ W, const float* __restrict__ bias,
    float* __restrict__ Out)
{
    __shared__ float af[8][3];
    const int t = threadIdx.x;
    const int yb = blockIdx.x * 8;

    if (t < 24) {
        const int yl = t / 3, c = t % 3;
        float s = 0.f;
        #pragma unroll
        for (int g = 0; g < NAGG; ++g)
            s += agg2[(size_t)g * ROWF + (yb + yl) * 3 + c];
        af[yl][c] = s;
    }
    __syncthreads();

    const int idx = blockIdx.x * 256 + t;
    const int y = idx >> 5;              // 8 y's per block
    const int o0 = (idx & 31) * 8;
    const int yl = y & 7;

    float s[8];
    #pragma unroll
    for (int j = 0; j < 8; ++j) s[j] = 0.f;
    #pragma unroll
    for (int sp = 0; sp < NSPLIT; ++sp) {
        const short8 v = *reinterpret_cast<const short8*>(
            gpart + (size_t)sp * NN * OO + (size_t)y * OO + o0);
        #pragma unroll
        for (int j = 0; j < 8; ++j)
            s[j] += bfs2f((unsigned short)v[j]);
    }

    const float a0 = af[yl][0], a1 = af[yl][1], a2 = af[yl][2];
    float r[8];
    #pragma unroll
    for (int j = 0; j < 8; ++j) {
        const int oo = o0 + j;
        r[j] = s[j] + a0 * W[(size_t)(DD + 0) * OO + oo]
                    + a1 * W[(size_t)(DD + 1) * OO + oo]
                    + a2 * W[(size_t)(DD + 2) * OO + oo]
                    + bias[oo];
    }
    float* od = Out + (size_t)y * OO + o0;
    *reinterpret_cast<f32x4*>(od)     = (f32x4){r[0], r[1], r[2], r[3]};
    *reinterpret_cast<f32x4*>(od + 4) = (f32x4){r[4], r[5], r[6], r[7]};
}

extern "C" void kernel_launch(void* const* d_in, const int* in_sizes, int n_in,
                              void* d_out, int out_size, void* d_ws, size_t ws_size,
                              hipStream_t stream) {
    (void)in_sizes; (void)n_in; (void)out_size; (void)ws_size;
    const float* adj  = (const float*)d_in[0];  // (N, N, C)
    const float* X    = (const float*)d_in[1];  // (N, D)
    const float* Beta = (const float*)d_in[2];  // (N, N)
    const float* W    = (const float*)d_in[3];  // (D+C, O)
    const float* bias = (const float*)d_in[4];  // (O)
    float* out = (float*)d_out;                 // (N, O) fp32

    const size_t xwt_b   = (size_t)OO * NN * 2;              // 2 MB
    const size_t gpart_b = (size_t)NSPLIT * NN * OO * 2;     // 16 MB
    const size_t apart_b = (size_t)NB2 * ROWF * 2;           // 12 MB

    char* p = (char*)d_ws;
    unsigned short* XWTb   = (unsigned short*)p;            p += xwt_b;
    unsigned short* gpart  = (unsigned short*)p;            p += gpart_b;
    unsigned short* apart  = (unsigned short*)p;            p += apart_b;
    float*          agg2   = (float*)p;                     // 1.5 MB

    const int clen = NN / NSPLIT;

    k1_xwt<<<dim3(NN / 8), dim3(256), 0, stream>>>(X, W, XWTb);
    k2_stream<<<dim3(NB2), dim3(1024), 0, stream>>>(adj, Beta, apart);
    k2b_reduce<<<dim3(6, NAGG), dim3(256), 0, stream>>>(apart, agg2);
    k4_gemm<<<dim3(NN / 64, NSPLIT), dim3(256), 0, stream>>>(Beta, XWTb, gpart, clen);
    k3_final<<<dim3(NN / 8), dim3(256), 0, stream>>>(gpart, agg2, W, bias, out);
}

// Round 17
// 99.025 us; speedup vs baseline: 2.4924x; 1.2043x over previous
//
#include <hip/hip_runtime.h>
#include <hip/hip_bf16.h>

#define NN 4096
#define DD 256
#define OO 256
#define NR 8                   // adjacency rows per K2 block
#define ROWF (NN * 3)          // floats per adjacency row
#define NSPLIT 8
#define NAGG 32                // k2b row-groups
#define NB2 (NN / NR)          // 512 k2 blocks

typedef __attribute__((ext_vector_type(4))) float f32x4;
typedef __attribute__((ext_vector_type(8))) short bf16x8;
typedef __attribute__((ext_vector_type(8))) short short8;
typedef __attribute__((ext_vector_type(4))) unsigned int u32x4;
typedef __attribute__((ext_vector_type(2))) unsigned int u32x2;

__device__ __forceinline__ short f2bfs(float f) {
    __hip_bfloat16 h = __float2bfloat16(f);
    short s;
    __builtin_memcpy(&s, &h, 2);
    return s;
}

__device__ __forceinline__ float bfs2f(unsigned short u) {
    unsigned int v = (unsigned int)u << 16;
    float f;
    __builtin_memcpy(&f, &v, 4);
    return f;
}

__device__ __forceinline__ unsigned pack2(float a, float b) {
    return (unsigned)(unsigned short)f2bfs(a)
         | ((unsigned)(unsigned short)f2bfs(b) << 16);
}

// K1: XWTb[m/8][o/16][16][8] bf16 = (X@Wf)[m][o] (k4 B-frag tiled). 512 blocks.
__global__ __launch_bounds__(256) void k1_xwt(
    const float* __restrict__ X, const float* __restrict__ W,
    unsigned short* __restrict__ XWTb)
{
    __shared__ float xs[8][DD];
    const int t = threadIdx.x;
    const int m0 = blockIdx.x * 8;

    #pragma unroll
    for (int i = 0; i < 8; ++i)
        xs[i][t] = X[(size_t)(m0 + i) * DD + t];
    __syncthreads();

    float acc[8];
    #pragma unroll
    for (int m = 0; m < 8; ++m) acc[m] = 0.f;

    for (int k0 = 0; k0 < DD; k0 += 4) {
        float w0 = W[(size_t)(k0 + 0) * OO + t];
        float w1 = W[(size_t)(k0 + 1) * OO + t];
        float w2 = W[(size_t)(k0 + 2) * OO + t];
        float w3 = W[(size_t)(k0 + 3) * OO + t];
        #pragma unroll
        for (int m = 0; m < 8; ++m) {
            const f32x4 xv = *reinterpret_cast<const f32x4*>(&xs[m][k0]);
            acc[m] = fmaf(xv[0], w0, acc[m]);
            acc[m] = fmaf(xv[1], w1, acc[m]);
            acc[m] = fmaf(xv[2], w2, acc[m]);
            acc[m] = fmaf(xv[3], w3, acc[m]);
        }
    }

    unsigned int p[4];
    #pragma unroll
    for (int i = 0; i < 4; ++i)
        p[i] = pack2(acc[2 * i], acc[2 * i + 1]);
    unsigned short* dst = XWTb
        + ((((size_t)(m0 >> 3) * (OO / 16) + (t >> 4)) * 16) + (t & 15)) * 8;
    *reinterpret_cast<u32x4*>(dst) = (u32x4){p[0], p[1], p[2], p[3]};
}

// K24: fused launch. Even blocks = k2 streaming (r16-proven body); odd blocks =
// k4 GEMM re-waved to 16 waves x 4 frags. At t=0: 256 stream + 256 MFMA blocks
// resident (2/CU); k4's L3-hit Beta/XWTb reads + MFMA hide under k2's HBM
// stream. Beta fetched once, L3-shared by both paths.
__global__ __launch_bounds__(1024, 8) void k24(
    const float* __restrict__ Adj, const float* __restrict__ Beta,
    const unsigned short* __restrict__ XWTb,
    unsigned short* __restrict__ apart, unsigned short* __restrict__ gpart)
{
    __shared__ unsigned short bsm16[NR * NN];   // 64 KB (k2 path only)
    const int t = threadIdx.x;

    if ((blockIdx.x & 1) == 0) {
        // ---------------- k2 path: probe-disciplined streamer ----------------
        const int nb = blockIdx.x >> 1;   // 0..511
        const int n0 = nb * NR;

        int fpos[3], y0[3], rr[3];
        #pragma unroll
        for (int p = 0; p < 3; ++p) {
            fpos[p] = p * NN + 4 * t;
            y0[p] = fpos[p] / 3;
            rr[p] = fpos[p] - 3 * y0[p];
        }

        f32x4 br[NR];
        #pragma unroll
        for (int n = 0; n < NR; ++n)
            br[n] = *reinterpret_cast<const f32x4*>(Beta + (size_t)(n0 + n) * NN + 4 * t);

        #pragma unroll
        for (int n = 0; n < NR; ++n) {
            const unsigned lo = pack2(br[n][0], br[n][1]);
            const unsigned hi = pack2(br[n][2], br[n][3]);
            *reinterpret_cast<u32x2*>(&bsm16[n * NN + 4 * t]) = (u32x2){lo, hi};
        }
        __syncthreads();

        f32x4 acc[3];
        #pragma unroll
        for (int p = 0; p < 3; ++p) acc[p] = (f32x4){0.f, 0.f, 0.f, 0.f};

        const float* arow = Adj + (size_t)n0 * ROWF;
        #pragma unroll 1
        for (int n = 0; n < NR; ++n) {
            f32x4 av[3];
            #pragma unroll
            for (int p = 0; p < 3; ++p)
                av[p] = __builtin_nontemporal_load(
                    reinterpret_cast<const f32x4*>(arow + fpos[p]));
            #pragma unroll
            for (int p = 0; p < 3; ++p) {
                const float bl = bfs2f(bsm16[n * NN + y0[p]]);
                const float bh = bfs2f(bsm16[n * NN + y0[p] + 1]);
                #pragma unroll
                for (int q = 0; q < 4; ++q) {
                    const float w = (rr[p] + q < 3) ? bl : bh;
                    acc[p][q] = fmaf(w, av[p][q], acc[p][q]);
                }
            }
            arow += ROWF;
        }

        unsigned short* op = apart + (size_t)nb * ROWF;
        #pragma unroll
        for (int p = 0; p < 3; ++p) {
            const unsigned lo = pack2(acc[p][0], acc[p][1]);
            const unsigned hi = pack2(acc[p][2], acc[p][3]);
            *reinterpret_cast<u32x2*>(op + fpos[p]) = (u32x2){lo, hi};
        }
    } else {
        // ---------------- k4 path: bf16 GEMM, 16 waves x 4 frags -------------
        const int kb = blockIdx.x >> 1;   // 0..511
        const int sp = kb & (NSPLIT - 1);
        const int by = kb >> 3;           // 0..63
        const int lane = t & 63;
        const int w = t >> 6;             // 0..15
        const int wy = w >> 2, wo = w & 3;
        const int g16 = lane >> 4, r16 = lane & 15;
        const int y0 = by * 64 + wy * 16;
        const int o0 = wo * 64;
        const int nb4 = sp * (NN / NSPLIT);
        const int ksteps = (NN / NSPLIT) / 32;   // 16

        f32x4 acc[4];
        #pragma unroll
        for (int f = 0; f < 4; ++f) acc[f] = (f32x4){0.f, 0.f, 0.f, 0.f};

        const float* bp = Beta + (size_t)(nb4 + 8 * g16) * NN + (y0 + r16);
        float bcur[8];
        #pragma unroll
        for (int j = 0; j < 8; ++j)
            bcur[j] = bp[(size_t)j * NN];

        for (int kc = 0; kc < ksteps; ++kc) {
            bf16x8 av;
            #pragma unroll
            for (int j = 0; j < 8; ++j)
                av[j] = f2bfs(bcur[j]);

            if (kc + 1 < ksteps) {
                const float* bn = bp + (size_t)(kc + 1) * 32 * NN;
                #pragma unroll
                for (int j = 0; j < 8; ++j)
                    bcur[j] = bn[(size_t)j * NN];
            }

            const int mc = ((nb4 >> 3) + kc * 4) + g16;
            const unsigned short* xb = XWTb
                + (((size_t)mc * 16 + (o0 >> 4)) * 16 + r16) * 8;
            #pragma unroll
            for (int f = 0; f < 4; ++f) {
                const bf16x8 bv = *reinterpret_cast<const bf16x8*>(xb + (size_t)f * 128);
                acc[f] = __builtin_amdgcn_mfma_f32_16x16x32_bf16(av, bv, acc[f], 0, 0, 0);
            }
        }

        unsigned short* gp = gpart + (size_t)sp * NN * OO;
        #pragma unroll
        for (int f = 0; f < 4; ++f) {
            const int o = o0 + 16 * f + r16;
            #pragma unroll
            for (int r = 0; r < 4; ++r)
                gp[(size_t)(y0 + 4 * g16 + r) * OO + o] = (unsigned short)f2bfs(acc[f][r]);
        }
    }
}

// K2b: agg2[g][i] = sum of 16 n-blocks of bf16 apart. grid (6, NAGG), short8 loads.
__global__ __launch_bounds__(256) void k2b_reduce(
    const unsigned short* __restrict__ apart, float* __restrict__ agg2)
{
    const int t = threadIdx.x;
    const int i0 = blockIdx.x * 2048 + t * 8;
    const int g = blockIdx.y;

    float s[8];
    #pragma unroll
    for (int j = 0; j < 8; ++j) s[j] = 0.f;

    #pragma unroll 4
    for (int r = 0; r < NB2 / NAGG; ++r) {
        const short8 v = *reinterpret_cast<const short8*>(
            apart + (size_t)(g * (NB2 / NAGG) + r) * ROWF + i0);
        #pragma unroll
        for (int j = 0; j < 8; ++j)
            s[j] += bfs2f((unsigned short)v[j]);
    }

    float* d = agg2 + (size_t)g * ROWF + i0;
    *reinterpret_cast<f32x4*>(d)     = (f32x4){s[0], s[1], s[2], s[3]};
    *reinterpret_cast<f32x4*>(d + 4) = (f32x4){s[4], s[5], s[6], s[7]};
}

// K3: out[y,o] = sum_sp gpart(bf16) + (sum_g agg2[g][y]) @ Wa + bias.
__global__ __launch_bounds__(256) void k3_final(
    const unsigned short* __restrict__ gpart, const float* __restrict__ agg2,
    const float* __restrict__ W, const float* __restrict__ bias,
    float* __restrict__ Out)
{
    __shared__ float af[8][3];
    const int t = threadIdx.x;
    const int yb = blockIdx.x * 8;

    if (t < 24) {
        const int yl = t / 3, c = t % 3;
        float s = 0.f;
        #pragma unroll
        for (int g = 0; g < NAGG; ++g)
            s += agg2[(size_t)g * ROWF + (yb + yl) * 3 + c];
        af[yl][c] = s;
    }
    __syncthreads();

    const int idx = blockIdx.x * 256 + t;
    const int y = idx >> 5;              // 8 y's per block
    const int o0 = (idx & 31) * 8;
    const int yl = y & 7;

    float s[8];
    #pragma unroll
    for (int j = 0; j < 8; ++j) s[j] = 0.f;
    #pragma unroll
    for (int sp = 0; sp < NSPLIT; ++sp) {
        const short8 v = *reinterpret_cast<const short8*>(
            gpart + (size_t)sp * NN * OO + (size_t)y * OO + o0);
        #pragma unroll
        for (int j = 0; j < 8; ++j)
            s[j] += bfs2f((unsigned short)v[j]);
    }

    const float a0 = af[yl][0], a1 = af[yl][1], a2 = af[yl][2];
    float r[8];
    #pragma unroll
    for (int j = 0; j < 8; ++j) {
        const int oo = o0 + j;
        r[j] = s[j] + a0 * W[(size_t)(DD + 0) * OO + oo]
                    + a1 * W[(size_t)(DD + 1) * OO + oo]
                    + a2 * W[(size_t)(DD + 2) * OO + oo]
                    + bias[oo];
    }
    float* od = Out + (size_t)y * OO + o0;
    *reinterpret_cast<f32x4*>(od)     = (f32x4){r[0], r[1], r[2], r[3]};
    *reinterpret_cast<f32x4*>(od + 4) = (f32x4){r[4], r[5], r[6], r[7]};
}

extern "C" void kernel_launch(void* const* d_in, const int* in_sizes, int n_in,
                              void* d_out, int out_size, void* d_ws, size_t ws_size,
                              hipStream_t stream) {
    (void)in_sizes; (void)n_in; (void)out_size; (void)ws_size;
    const float* adj  = (const float*)d_in[0];  // (N, N, C)
    const float* X    = (const float*)d_in[1];  // (N, D)
    const float* Beta = (const float*)d_in[2];  // (N, N)
    const float* W    = (const float*)d_in[3];  // (D+C, O)
    const float* bias = (const float*)d_in[4];  // (O)
    float* out = (float*)d_out;                 // (N, O) fp32

    const size_t xwt_b   = (size_t)OO * NN * 2;              // 2 MB
    const size_t gpart_b = (size_t)NSPLIT * NN * OO * 2;     // 16 MB
    const size_t apart_b = (size_t)NB2 * ROWF * 2;           // 12 MB

    char* p = (char*)d_ws;
    unsigned short* XWTb   = (unsigned short*)p;            p += xwt_b;
    unsigned short* gpart  = (unsigned short*)p;            p += gpart_b;
    unsigned short* apart  = (unsigned short*)p;            p += apart_b;
    float*          agg2   = (float*)p;                     // 1.5 MB

    k1_xwt<<<dim3(NN / 8), dim3(256), 0, stream>>>(X, W, XWTb);
    k24<<<dim3(2 * NB2), dim3(1024), 0, stream>>>(adj, Beta, XWTb, apart, gpart);
    k2b_reduce<<<dim3(6, NAGG), dim3(256), 0, stream>>>(apart, agg2);
    k3_final<<<dim3(NN / 8), dim3(256), 0, stream>>>(gpart, agg2, W, bias, out);
}